// Round 4
// baseline (39.205 us; speedup 1.0000x reference)
//
#include <hip/hip_runtime.h>
#include <math.h>

// Problem constants (from reference): B=16, D=128, T=512.
#define B_DIM 16
#define D_DIM 128
#define T_DIM 512
#define NT4   128     // float4 per T-row
#define PAD   132     // s_w row pad in floats; %4==0 keeps b128 16B-aligned

// ---------------------------------------------------------------------------
// Single kernel, producer/consumer over workspace with bounded-spin + fallback.
//
// Block = (b = bid&15, c = bid>>4).  16≡0 (mod 8) => all blocks of batch b on
// XCD b%8: the vec/flags handshake and all K/V reuse stay inside one L2.
//
// Stage 1 (produce): block sums combined rows [c*16, c*16+16) of [Q;K] for
//   batch b (each Q/K row read ONCE globally), writes 16 floats to ws vec,
//   then threadfence + release atomicAdd(flags[b]).
// Stage 2 (sync): spin (bounded) until flags[b]==16; on timeout, recompute all
//   256 sums locally (correctness never depends on co-residency).
// Stage 3 (softmax): all 128 rows; logit = para0/(T*sqrt(T))*qs_i*ks_j*p2_ij
//   (irfft().mean() keeps only DC/T). |logit| <~ 1 so no max-subtraction.
//   Weights to s_w[i][j] (pad 132: conflict-free writes and b128 reads).
// Stage 4 (matmul slice): out[b, :, c*32..c*32+31] = attn x values-slice.
//   Each values element is read once TOTAL across the grid; per wave the v
//   loads hit only 8 unique 16B addresses (lane-merged, L1-served).
// ---------------------------------------------------------------------------
__global__ __launch_bounds__(512) void fused_kernel(
    const float* __restrict__ queries,
    const float* __restrict__ keys,
    const float* __restrict__ values,
    const float* __restrict__ para,
    const float* __restrict__ para2,
    float* __restrict__ vec,        // ws: [16][256]  (qsum 0..127 | ksum 128..255)
    unsigned* __restrict__ flags,   // ws: [16], zeroed by memset node each launch
    float* __restrict__ out) {

    int bid = blockIdx.x;
    int b   = bid & 15;
    int c   = bid >> 4;            // 0..15: row-chunk (stage 1) and t-chunk (stage 4)
    int tid = threadIdx.x;

    __shared__ float s_vec[256];
    __shared__ float s_w[D_DIM][PAD];
    __shared__ int s_ready;

    // ---- Stage 1: produce row-sums [c*16, c*16+16) of [Q;K] ----
    {
        int row = tid >> 5;        // 0..15
        int sub = tid & 31;        // 32 lanes per row -> 4 float4 each
        int grow = c * 16 + row;   // 0..255 combined index
        const float* src = (grow < D_DIM)
            ? queries + ((size_t)b * D_DIM + grow) * T_DIM
            : keys + ((size_t)b * D_DIM + (grow - D_DIM)) * T_DIM;
        const float4* s4 = reinterpret_cast<const float4*>(src);
        float s = 0.f;
        #pragma unroll
        for (int k = 0; k < 4; ++k) {
            float4 v = s4[sub + 32 * k];
            s += (v.x + v.y) + (v.z + v.w);
        }
        #pragma unroll
        for (int off = 16; off > 0; off >>= 1) s += __shfl_xor(s, off, 64);
        if (sub == 0) vec[b * 256 + grow] = s;
    }
    __syncthreads();

    // ---- Stage 2: publish + bounded spin ----
    if (tid == 0) {
        __threadfence();
        __hip_atomic_fetch_add(&flags[b], 1u, __ATOMIC_RELEASE, __HIP_MEMORY_SCOPE_AGENT);
        unsigned v;
        int it = 0;
        do {
            v = __hip_atomic_load(&flags[b], __ATOMIC_ACQUIRE, __HIP_MEMORY_SCOPE_AGENT);
        } while (v < 16u && ++it < (1 << 17));
        s_ready = (v >= 16u) ? 1 : 0;
    }
    __syncthreads();

    if (s_ready) {
        if (tid < 256) s_vec[tid] = vec[b * 256 + tid];
    } else {
        // Fallback: compute all 256 sums locally (identical summation order).
        int row = tid >> 5;
        int sub = tid & 31;
        for (int cc = 0; cc < 16; ++cc) {
            int grow = cc * 16 + row;
            const float* src = (grow < D_DIM)
                ? queries + ((size_t)b * D_DIM + grow) * T_DIM
                : keys + ((size_t)b * D_DIM + (grow - D_DIM)) * T_DIM;
            const float4* s4 = reinterpret_cast<const float4*>(src);
            float s = 0.f;
            #pragma unroll
            for (int k = 0; k < 4; ++k) {
                float4 v = s4[sub + 32 * k];
                s += (v.x + v.y) + (v.z + v.w);
            }
            #pragma unroll
            for (int off = 16; off > 0; off >>= 1) s += __shfl_xor(s, off, 64);
            if (sub == 0) s_vec[grow] = s;
        }
    }
    __syncthreads();

    // ---- Stage 3: softmax for all 128 rows; wave w owns rows w*16..+15 ----
    {
        int wave = tid >> 6;
        int lane = tid & 63;
        float cscale = para[0] / (512.0f * sqrtf(512.0f));
        for (int rr = 0; rr < 16; ++rr) {
            int i = wave * 16 + rr;
            float qc = cscale * s_vec[i];
            float l0 = qc * s_vec[128 + lane] * para2[i * D_DIM + lane];
            float l1 = qc * s_vec[128 + lane + 64] * para2[i * D_DIM + lane + 64];
            float e0 = __expf(l0);
            float e1 = __expf(l1);
            float s = e0 + e1;
            #pragma unroll
            for (int off = 32; off > 0; off >>= 1) s += __shfl_xor(s, off, 64);
            float inv = 1.0f / s;
            s_w[i][lane] = e0 * inv;
            s_w[i][lane + 64] = e1 * inv;
        }
    }
    __syncthreads();

    // ---- Stage 4: out[b, :, c*32..+31] = attn x values[:, slice] ----
    {
        int ig = tid >> 3;         // 0..63 -> rows 2ig, 2ig+1
        int t4 = tid & 7;          // float4 within the 32-float slice
        int i0 = ig * 2;
        const float4* v4 = reinterpret_cast<const float4*>(values);
        size_t vbase = (size_t)b * D_DIM * NT4 + (size_t)c * 8 + t4;
        float4 a0 = make_float4(0.f, 0.f, 0.f, 0.f);
        float4 a1 = make_float4(0.f, 0.f, 0.f, 0.f);
        const float4* w0p = reinterpret_cast<const float4*>(&s_w[i0][0]);
        const float4* w1p = reinterpret_cast<const float4*>(&s_w[i0 + 1][0]);

        #define FMA4(A, W, V) \
            A.x += (W) * (V).x; A.y += (W) * (V).y; A.z += (W) * (V).z; A.w += (W) * (V).w;

        #pragma unroll 4
        for (int j4 = 0; j4 < 32; ++j4) {
            float4 w0 = w0p[j4];
            float4 w1 = w1p[j4];
            float4 v0 = v4[vbase + (size_t)(4 * j4 + 0) * NT4];
            float4 v1 = v4[vbase + (size_t)(4 * j4 + 1) * NT4];
            float4 v2 = v4[vbase + (size_t)(4 * j4 + 2) * NT4];
            float4 v3 = v4[vbase + (size_t)(4 * j4 + 3) * NT4];
            FMA4(a0, w0.x, v0) FMA4(a0, w0.y, v1) FMA4(a0, w0.z, v2) FMA4(a0, w0.w, v3)
            FMA4(a1, w1.x, v0) FMA4(a1, w1.y, v1) FMA4(a1, w1.z, v2) FMA4(a1, w1.w, v3)
        }
        #undef FMA4

        float4* o4 = reinterpret_cast<float4*>(out);
        size_t ob = (size_t)(b * D_DIM + i0) * NT4 + (size_t)c * 8 + t4;
        o4[ob] = a0;
        o4[ob + NT4] = a1;
    }
}

extern "C" void kernel_launch(void* const* d_in, const int* in_sizes, int n_in,
                              void* d_out, int out_size, void* d_ws, size_t ws_size,
                              hipStream_t stream) {
    const float* queries = (const float*)d_in[0];  // [B, D, T]
    const float* keys    = (const float*)d_in[1];  // [B, D, T]
    const float* values  = (const float*)d_in[2];  // [B, D, T]
    // d_in[3] = attn_mask (unused)
    const float* para    = (const float*)d_in[4];  // [25]
    const float* para2   = (const float*)d_in[5];  // [D, D]
    float* out = (float*)d_out;                    // [B, D, T] fp32

    float* vec = (float*)d_ws;                                        // 16*256 floats
    unsigned* flags = (unsigned*)((char*)d_ws + 16 * 256 * sizeof(float));  // 16 uints

    hipMemsetAsync(flags, 0, 16 * sizeof(unsigned), stream);
    fused_kernel<<<B_DIM * 16, 512, 0, stream>>>(queries, keys, values, para, para2,
                                                 vec, flags, out);
}